// Round 1
// baseline (36.150 us; speedup 1.0000x reference)
//
#include <hip/hip_runtime.h>
#include <math.h>

#define IN_DIM 128
#define OUT_DIM 64
#define TARGET_LEN 8192
#define NEIGHBOR_LEN 16384
#define DEG 32
#define E_EDGES (TARGET_LEN * DEG)
#define ALPHA 0.2f

__device__ __forceinline__ float leaky(float x) { return x > 0.f ? x : ALPHA * x; }
__device__ __forceinline__ float elu1(float x)  { return x > 0.f ? x : expm1f(x); }

// Stage 1: h = features@W (rows 0..16383), nl_h = nl_features[nit]@W (rows 16384..24575)
// plus s1 = h@a1, s2 = h@a2, nl_s2 = nl_h@a2, out1 = elu(nl_h).
// One wave per row; lane = output column; W column held in registers.
__global__ __launch_bounds__(256) void gat_stage1(
    const float* __restrict__ features,
    const float* __restrict__ nl_features,
    const float* __restrict__ W,
    const float* __restrict__ a,
    const int*  __restrict__ nit,
    float* __restrict__ h,
    float* __restrict__ nl_h,
    float* __restrict__ s1,
    float* __restrict__ s2,
    float* __restrict__ nl_s2,
    float* __restrict__ out1)
{
    __shared__ float frow[4][IN_DIM];
    const int tid  = threadIdx.x;
    const int lane = tid & 63;
    const int wv   = tid >> 6;

    // W column for this lane in registers (full unroll -> static indexing, stays in VGPRs)
    float wcol[IN_DIM];
    #pragma unroll
    for (int k = 0; k < IN_DIM; ++k) wcol[k] = W[k * OUT_DIM + lane];
    const float a1 = a[lane];
    const float a2 = a[OUT_DIM + lane];

    const int nwaves = gridDim.x * 4;            // 512 blocks * 4 waves = 2048
    const int gwave  = blockIdx.x * 4 + wv;
    const int TOTAL  = NEIGHBOR_LEN + TARGET_LEN; // 24576, divisible by 2048 -> uniform trip count

    for (int r = gwave; r < TOTAL; r += nwaves) {
        const float* src;
        if (r < NEIGHBOR_LEN) {
            src = features + (size_t)r * IN_DIM;
        } else {
            int t = r - NEIGHBOR_LEN;
            src = nl_features + (size_t)nit[t] * IN_DIM;
        }
        float f0 = src[lane];
        float f1 = src[64 + lane];
        frow[wv][lane]      = f0;
        frow[wv][64 + lane] = f1;
        __syncthreads();   // uniform trip count across all 4 waves (24576 % 2048 == 0)

        float acc = 0.f;
        #pragma unroll
        for (int k = 0; k < IN_DIM; ++k)
            acc = fmaf(frow[wv][k], wcol[k], acc);

        if (r < NEIGHBOR_LEN) {
            h[(size_t)r * OUT_DIM + lane] = acc;
            float p1 = acc * a1;
            float p2 = acc * a2;
            #pragma unroll
            for (int d = 32; d >= 1; d >>= 1) {
                p1 += __shfl_xor(p1, d, 64);
                p2 += __shfl_xor(p2, d, 64);
            }
            if (lane == 0) { s1[r] = p1; s2[r] = p2; }
        } else {
            int t = r - NEIGHBOR_LEN;
            nl_h[(size_t)t * OUT_DIM + lane] = acc;
            out1[(size_t)t * OUT_DIM + lane] = elu1(acc);
            float p2 = acc * a2;
            #pragma unroll
            for (int d = 32; d >= 1; d >>= 1) p2 += __shfl_xor(p2, d, 64);
            if (lane == 0) nl_s2[t] = p2;
        }
        __syncthreads();   // protect frow reuse across iterations (cross-wave lockstep)
    }
}

// Stage 2: per target row, 33-way softmax + weighted gather of h rows + ELU.
// One wave per row. Lanes 0..31 own edges; lane = output column for the gather.
__global__ __launch_bounds__(256) void gat_stage2(
    const int*  __restrict__ adj,     // [2][E]
    const int*  __restrict__ nit,
    const float* __restrict__ h,
    const float* __restrict__ nl_h,
    const float* __restrict__ s1,
    const float* __restrict__ s2,
    const float* __restrict__ nl_s2,
    float* __restrict__ out0)
{
    __shared__ float sw[4][DEG];
    __shared__ int   sc[4][DEG];
    const int tid  = threadIdx.x;
    const int lane = tid & 63;
    const int wv   = tid >> 6;
    const int t    = blockIdx.x * 4 + wv;   // grid = 2048 -> t in [0, 8192): no early-exit

    float ev = -1e30f;
    int   cj = 0;
    if (lane < DEG) {
        int i  = t * DEG + lane;
        int a0 = adj[i];
        cj     = adj[E_EDGES + i];
        ev     = leaky(s1[a0] + s2[cj]);
    }
    float nle = leaky(s1[nit[t]] + nl_s2[t]);

    float m = ev;
    #pragma unroll
    for (int d = 32; d >= 1; d >>= 1) m = fmaxf(m, __shfl_xor(m, d, 64));
    m = fmaxf(m, nle);

    float w  = (lane < DEG) ? __expf(ev - m) : 0.f;
    float wn = __expf(nle - m);
    float ssum = w;
    #pragma unroll
    for (int d = 32; d >= 1; d >>= 1) ssum += __shfl_xor(ssum, d, 64);
    float inv = 1.f / (ssum + wn);

    if (lane < DEG) { sw[wv][lane] = w; sc[wv][lane] = cj; }
    __syncthreads();   // all waves always reach here (no divergent exit)

    float acc = wn * nl_h[(size_t)t * OUT_DIM + lane];
    #pragma unroll
    for (int j = 0; j < DEG; ++j)
        acc = fmaf(sw[wv][j], h[(size_t)sc[wv][j] * OUT_DIM + lane], acc);

    out0[(size_t)t * OUT_DIM + lane] = elu1(acc * inv);
}

extern "C" void kernel_launch(void* const* d_in, const int* in_sizes, int n_in,
                              void* d_out, int out_size, void* d_ws, size_t ws_size,
                              hipStream_t stream) {
    const float* features    = (const float*)d_in[0];
    const float* nl_features = (const float*)d_in[1];
    const float* W           = (const float*)d_in[2];
    const float* a           = (const float*)d_in[3];
    const int*   adj         = (const int*)d_in[4];
    // d_in[5] target_index_out: implied by i/DEG, unused
    const int*   nit         = (const int*)d_in[6];
    // d_in[7], d_in[8]: scalar lens, fixed at compile time

    float* ws    = (float*)d_ws;
    float* h     = ws;                                   // 16384*64
    float* nl_h  = h    + (size_t)NEIGHBOR_LEN * OUT_DIM; // 8192*64
    float* s1    = nl_h + (size_t)TARGET_LEN  * OUT_DIM;  // 16384
    float* s2    = s1 + NEIGHBOR_LEN;                     // 16384
    float* nl_s2 = s2 + NEIGHBOR_LEN;                     // 8192

    float* out0 = (float*)d_out;
    float* out1 = out0 + (size_t)TARGET_LEN * OUT_DIM;

    hipLaunchKernelGGL(gat_stage1, dim3(512), dim3(256), 0, stream,
                       features, nl_features, W, a, nit, h, nl_h, s1, s2, nl_s2, out1);
    hipLaunchKernelGGL(gat_stage2, dim3(TARGET_LEN / 4), dim3(256), 0, stream,
                       adj, nit, h, nl_h, s1, s2, nl_s2, out0);
}

// Round 2
// 20.827 us; speedup vs baseline: 1.7357x; 1.7357x over previous
//
#include <hip/hip_runtime.h>
#include <math.h>

#define IN_DIM 128
#define OUT_DIM 64
#define TARGET_LEN 8192
#define NEIGHBOR_LEN 16384
#define DEG 32
#define E_EDGES (TARGET_LEN * DEG)
#define ALPHA 0.2f

typedef __attribute__((ext_vector_type(8))) short bf16x8;
typedef __attribute__((ext_vector_type(4))) float f32x4;

__device__ __forceinline__ float leaky(float x) { return x > 0.f ? x : ALPHA * x; }
__device__ __forceinline__ float elu1(float x)  { return x > 0.f ? x : expm1f(x); }

// round-to-nearest-even f32 -> bf16 bits (inputs are normal randoms; no NaN/denorm concerns)
__device__ __forceinline__ short f2bf(float x) {
    unsigned u = __float_as_uint(x);
    unsigned r = (u + 0x7FFFu + ((u >> 16) & 1u)) >> 16;
    return (short)r;
}

// Stage 1 (MFMA): one wave per 16-row tile.
// Tiles 0..1023: h = features@W  (rows 16*tile .. 16*tile+15)
// Tiles 1024..1535: nl_h = nl_features[nit]@W (targets 16*(tile-1024) ...)
// Epilogue: s1=h@a1, s2=h@a2 (feature tiles); nl_s2=nl_h@a2, out1=elu(nl_h) (nl tiles).
// No LDS, no barriers.  MFMA layout (m89-verified):
//   A: row=lane&15,  k=8*(lane>>4)+b   B: col=lane&15, k=8*(lane>>4)+b
//   D: col=lane&15, row=4*(lane>>4)+b
__global__ __launch_bounds__(64) void gat_stage1(
    const float* __restrict__ features,
    const float* __restrict__ nl_features,
    const float* __restrict__ W,
    const float* __restrict__ a,
    const int*  __restrict__ nit,
    float* __restrict__ h,
    float* __restrict__ nl_h,
    float* __restrict__ s1,
    float* __restrict__ s2,
    float* __restrict__ nl_s2,
    float* __restrict__ out1)
{
    const int lane = threadIdx.x;      // 0..63
    const int tile = blockIdx.x;       // 0..1535
    const int r16  = lane & 15;
    const int g    = lane >> 4;        // 0..3
    const bool isNL = (tile >= NEIGHBOR_LEN / 16);
    const int rowbase = tile * 16;

    // --- B fragments: wf[ks][nt][b] = bf16( W[(32*ks + 8*g + b)*64 + 16*nt + r16] )
    bf16x8 wf[4][4];
    #pragma unroll
    for (int ks = 0; ks < 4; ++ks) {
        #pragma unroll
        for (int nt = 0; nt < 4; ++nt) {
            #pragma unroll
            for (int b = 0; b < 8; ++b) {
                wf[ks][nt][b] = f2bf(W[(32 * ks + 8 * g + b) * OUT_DIM + 16 * nt + r16]);
            }
        }
    }

    // --- A row pointer for this lane (row r16 of the tile)
    const float* srcrow;
    if (!isNL) {
        srcrow = features + (size_t)(rowbase + r16) * IN_DIM;
    } else {
        int t = rowbase - NEIGHBOR_LEN + r16;
        srcrow = nl_features + (size_t)nit[t] * IN_DIM;
    }

    // --- A fragments: af[ks][b] = bf16( srcrow[32*ks + 8*g + b] ), loaded as 2x float4
    bf16x8 af[4];
    #pragma unroll
    for (int ks = 0; ks < 4; ++ks) {
        float4 u0 = *(const float4*)(srcrow + 32 * ks + 8 * g);
        float4 u1 = *(const float4*)(srcrow + 32 * ks + 8 * g + 4);
        af[ks][0] = f2bf(u0.x); af[ks][1] = f2bf(u0.y);
        af[ks][2] = f2bf(u0.z); af[ks][3] = f2bf(u0.w);
        af[ks][4] = f2bf(u1.x); af[ks][5] = f2bf(u1.y);
        af[ks][6] = f2bf(u1.z); af[ks][7] = f2bf(u1.w);
    }

    // --- MFMA: acc[nt] over 4 K-steps (accumulate into same acc, K-loop recipe)
    f32x4 acc[4] = {};
    #pragma unroll
    for (int ks = 0; ks < 4; ++ks) {
        #pragma unroll
        for (int nt = 0; nt < 4; ++nt) {
            acc[nt] = __builtin_amdgcn_mfma_f32_16x16x32_bf16(af[ks], wf[ks][nt], acc[nt], 0, 0, 0);
        }
    }

    // --- epilogue: s1/s2 dots. Lane holds D[4*g+b][16*nt+r16] = acc[nt][b].
    float a1v[4], a2v[4];
    #pragma unroll
    for (int nt = 0; nt < 4; ++nt) {
        a1v[nt] = a[16 * nt + r16];
        a2v[nt] = a[OUT_DIM + 16 * nt + r16];
    }
    float p1[4] = {0.f, 0.f, 0.f, 0.f};
    float p2[4] = {0.f, 0.f, 0.f, 0.f};
    #pragma unroll
    for (int nt = 0; nt < 4; ++nt) {
        #pragma unroll
        for (int b = 0; b < 4; ++b) {
            p1[b] = fmaf(acc[nt][b], a1v[nt], p1[b]);
            p2[b] = fmaf(acc[nt][b], a2v[nt], p2[b]);
        }
    }
    // reduce across the 16 lanes of each g-group (xor 1,2,4,8 stays in-group)
    #pragma unroll
    for (int d = 1; d <= 8; d <<= 1) {
        #pragma unroll
        for (int b = 0; b < 4; ++b) {
            p1[b] += __shfl_xor(p1[b], d, 64);
            p2[b] += __shfl_xor(p2[b], d, 64);
        }
    }

    // --- stores
    if (!isNL) {
        #pragma unroll
        for (int nt = 0; nt < 4; ++nt)
            #pragma unroll
            for (int b = 0; b < 4; ++b)
                h[(size_t)(rowbase + 4 * g + b) * OUT_DIM + 16 * nt + r16] = acc[nt][b];
        if (r16 == 0) {
            #pragma unroll
            for (int b = 0; b < 4; ++b) {
                s1[rowbase + 4 * g + b] = p1[b];
                s2[rowbase + 4 * g + b] = p2[b];
            }
        }
    } else {
        const int tb = rowbase - NEIGHBOR_LEN;
        #pragma unroll
        for (int nt = 0; nt < 4; ++nt) {
            #pragma unroll
            for (int b = 0; b < 4; ++b) {
                float v = acc[nt][b];
                size_t idx = (size_t)(tb + 4 * g + b) * OUT_DIM + 16 * nt + r16;
                nl_h[idx] = v;
                out1[idx] = elu1(v);
            }
        }
        if (r16 == 0) {
            #pragma unroll
            for (int b = 0; b < 4; ++b)
                nl_s2[tb + 4 * g + b] = p2[b];
        }
    }
}

// Stage 2: per target row, 33-way softmax + weighted gather of h rows + ELU.
// One wave per row. Lanes 0..31 own edges; lane = output column for the gather.
__global__ __launch_bounds__(256) void gat_stage2(
    const int*  __restrict__ adj,     // [2][E]
    const int*  __restrict__ nit,
    const float* __restrict__ h,
    const float* __restrict__ nl_h,
    const float* __restrict__ s1,
    const float* __restrict__ s2,
    const float* __restrict__ nl_s2,
    float* __restrict__ out0)
{
    __shared__ float sw[4][DEG];
    __shared__ int   sc[4][DEG];
    const int tid  = threadIdx.x;
    const int lane = tid & 63;
    const int wv   = tid >> 6;
    const int t    = blockIdx.x * 4 + wv;   // grid = 2048 -> t in [0, 8192): no early-exit

    float ev = -1e30f;
    int   cj = 0;
    if (lane < DEG) {
        int i  = t * DEG + lane;
        int a0 = adj[i];
        cj     = adj[E_EDGES + i];
        ev     = leaky(s1[a0] + s2[cj]);
    }
    float nle = leaky(s1[nit[t]] + nl_s2[t]);

    float m = ev;
    #pragma unroll
    for (int d = 32; d >= 1; d >>= 1) m = fmaxf(m, __shfl_xor(m, d, 64));
    m = fmaxf(m, nle);

    float w  = (lane < DEG) ? __expf(ev - m) : 0.f;
    float wn = __expf(nle - m);
    float ssum = w;
    #pragma unroll
    for (int d = 32; d >= 1; d >>= 1) ssum += __shfl_xor(ssum, d, 64);
    float inv = 1.f / (ssum + wn);

    if (lane < DEG) { sw[wv][lane] = w; sc[wv][lane] = cj; }
    __syncthreads();   // all waves always reach here (no divergent exit)

    float acc = wn * nl_h[(size_t)t * OUT_DIM + lane];
    #pragma unroll
    for (int j = 0; j < DEG; ++j)
        acc = fmaf(sw[wv][j], h[(size_t)sc[wv][j] * OUT_DIM + lane], acc);

    out0[(size_t)t * OUT_DIM + lane] = elu1(acc * inv);
}

extern "C" void kernel_launch(void* const* d_in, const int* in_sizes, int n_in,
                              void* d_out, int out_size, void* d_ws, size_t ws_size,
                              hipStream_t stream) {
    const float* features    = (const float*)d_in[0];
    const float* nl_features = (const float*)d_in[1];
    const float* W           = (const float*)d_in[2];
    const float* a           = (const float*)d_in[3];
    const int*   adj         = (const int*)d_in[4];
    // d_in[5] target_index_out: implied by i/DEG, unused
    const int*   nit         = (const int*)d_in[6];
    // d_in[7], d_in[8]: scalar lens, fixed at compile time

    float* ws    = (float*)d_ws;
    float* h     = ws;                                    // 16384*64
    float* nl_h  = h    + (size_t)NEIGHBOR_LEN * OUT_DIM; // 8192*64
    float* s1    = nl_h + (size_t)TARGET_LEN  * OUT_DIM;  // 16384
    float* s2    = s1 + NEIGHBOR_LEN;                     // 16384
    float* nl_s2 = s2 + NEIGHBOR_LEN;                     // 8192

    float* out0 = (float*)d_out;
    float* out1 = out0 + (size_t)TARGET_LEN * OUT_DIM;

    hipLaunchKernelGGL(gat_stage1, dim3((NEIGHBOR_LEN + TARGET_LEN) / 16), dim3(64), 0, stream,
                       features, nl_features, W, a, nit, h, nl_h, s1, s2, nl_s2, out1);
    hipLaunchKernelGGL(gat_stage2, dim3(TARGET_LEN / 4), dim3(256), 0, stream,
                       adj, nit, h, nl_h, s1, s2, nl_s2, out0);
}